// Round 6
// baseline (585.165 us; speedup 1.0000x reference)
//
#include <hip/hip_runtime.h>
#include <hip/hip_cooperative_groups.h>

namespace cg = cooperative_groups;

// segments: (8, 1, 512, 512) f32, values 0..63; downsample ::2 -> (8, 256, 256)
// R=7, K_SIDE=15, 225 offsets, zero-padded OOB (pad=0.0 CAN match seg==0)
// out: (8, 225, 256, 256) f32 = 471.9 MB -> write floor ~75 us @ 6.3 TB/s
//
// R8: ENFORCED CONVOY. R2/R3f/R7 all cap at ~160us = 2.95 TB/s despite
// different per-wave patterns -> the limiter is aggregate address density:
// with ~256B channel interleave, a DRAM row per pseudo-channel spans a
// ~256KB dense window and each PC has ~16 banks, so row amortization needs
// the WHOLE GPU's instantaneous store set inside <=16 dense windows. fill
// (uniform work, uniform backpressure) stays in lockstep and gets 6.3 TB/s;
// R7's uncoupled blocks drifted across the full 471.9 MB.
// Here: 256 blocks (1/CU) x 512 thr; block = (batch, 8-row band); stage the
// 22-row halo once (R7's staging); all blocks walk planes p=0..224 in the
// same order -> at any instant 8 dense 256KB windows (one per batch).
// Lockstep enforced: identical per-iter work, raw s_barrier per plane
// (no vmcnt drain), grid.sync() every 45 planes (4 syncs). Plain stores.

#define RAD 7
#define KS 15
#define HW 256
#define IN_W 512
#define PLANE (HW * HW)         // 65536
#define CH 8                    // rows per band = waves per block
#define SROWS (CH + 2 * RAD)    // 22
#define SPITCH 272              // 8 left pad + 256 + 8 right pad
#define NPAIR (SPITCH / 2)      // 136
#define NTASK (SROWS * NPAIR)   // 2992
#define SYNC_K 45               // grid sync period (225/45 = 5 epochs)

typedef float vf4 __attribute__((ext_vector_type(4)));

__global__ __launch_bounds__(512) void adj_convoy(const float* __restrict__ in,
                                                  float* __restrict__ out,
                                                  int use_gsync) {
    __shared__ float smem[SROWS][SPITCH];   // 23,936 B

    const int g    = blockIdx.x;            // 0..255
    const int b    = g >> 5;                // batch 0..7
    const int band = g & 31;                // 0..31
    const int y0   = band * CH;
    const int tid  = threadIdx.x;

    const float* inb = in + (size_t)b * (IN_W * IN_W);

    // Stage ds rows [y0-7, y0+14] x ds cols [-8, 263], zero-padded.
    // LDS col pair (2pr, 2pr+1) = ds cols (2pr-8, 2pr-7) from one aligned
    // full-res vf4 (even elements = stride-2 downsample).
    for (int i = tid; i < NTASK; i += 512) {
        const int r  = i / NPAIR;
        const int pr = i - r * NPAIR;
        const int gy = y0 - RAD + r;        // ds row
        const int c0 = 2 * pr - 8;          // first ds col of pair
        float v0 = 0.0f, v1 = 0.0f;
        if ((unsigned)gy < (unsigned)HW && (unsigned)c0 < (unsigned)HW) {
            const vf4 q = *(const vf4*)(inb + (size_t)(2 * gy) * IN_W + 2 * c0);
            v0 = q.x;
            v1 = q.z;
        }
        smem[r][2 * pr]     = v0;
        smem[r][2 * pr + 1] = v1;
    }
    __syncthreads();

    const int wv   = tid >> 6;              // 0..7: row within band
    const int lane = tid & 63;
    const int x    = lane * 4;              // 4 output columns

    // own segment ids: fixed per wave, hoisted
    const vf4 own = *(const vf4*)&smem[wv + RAD][8 + x];
    const float s0 = own.x, s1 = own.y, s2 = own.z, s3 = own.w;

    float* op = out + (size_t)b * (KS * KS) * (size_t)PLANE
                    + (size_t)(y0 + wv) * HW + x;

    int dy = 0, dx = 0;
    for (int p = 0; p < KS * KS; ++p, op += PLANE) {
        // neighbor (y0+wv+dy-7, x+k+dx-7) -> LDS row wv+dy, col x+dx+1+k
        const float* nrow = &smem[wv + dy][0];
        const int d4 = (dx + 1) & ~3;       // aligned start
        const vf4 w0 = *(const vf4*)(nrow + x + d4);
        const vf4 w1 = *(const vf4*)(nrow + x + d4 + 4);
        vf4 r;
        switch ((dx + 1) & 3) {             // wave-uniform select
        case 0:
            r.x = (s0 == w0.x) ? 1.f : 0.f; r.y = (s1 == w0.y) ? 1.f : 0.f;
            r.z = (s2 == w0.z) ? 1.f : 0.f; r.w = (s3 == w0.w) ? 1.f : 0.f;
            break;
        case 1:
            r.x = (s0 == w0.y) ? 1.f : 0.f; r.y = (s1 == w0.z) ? 1.f : 0.f;
            r.z = (s2 == w0.w) ? 1.f : 0.f; r.w = (s3 == w1.x) ? 1.f : 0.f;
            break;
        case 2:
            r.x = (s0 == w0.z) ? 1.f : 0.f; r.y = (s1 == w0.w) ? 1.f : 0.f;
            r.z = (s2 == w1.x) ? 1.f : 0.f; r.w = (s3 == w1.y) ? 1.f : 0.f;
            break;
        default:
            r.x = (s0 == w0.w) ? 1.f : 0.f; r.y = (s1 == w1.x) ? 1.f : 0.f;
            r.z = (s2 == w1.y) ? 1.f : 0.f; r.w = (s3 == w1.z) ? 1.f : 0.f;
            break;
        }
        *(vf4*)op = r;                      // plain store (match fill)

        if (++dx == KS) { dx = 0; ++dy; }

        // intra-block lockstep: raw barrier, NO vmcnt drain
        __builtin_amdgcn_s_barrier();
        // inter-block lockstep: re-converge every SYNC_K planes
        if (use_gsync && (p % SYNC_K) == (SYNC_K - 1) && p != KS * KS - 1) {
            cg::this_grid().sync();
        }
    }
}

extern "C" void kernel_launch(void* const* d_in, const int* in_sizes, int n_in,
                              void* d_out, int out_size, void* d_ws, size_t ws_size,
                              hipStream_t stream) {
    const float* segments = (const float*)d_in[0];
    float* out = (float*)d_out;
    int use_gsync = 1;
    void* args[] = { (void*)&segments, (void*)&out, (void*)&use_gsync };
    hipError_t e = hipLaunchCooperativeKernel((void*)adj_convoy,
                                              dim3(256), dim3(512),
                                              args, 0, stream);
    if (e != hipSuccess) {
        // cooperative launch unavailable: same kernel, grid syncs disabled
        adj_convoy<<<dim3(256), dim3(512), 0, stream>>>(segments, out, 0);
    }
}

// Round 7
// 456.111 us; speedup vs baseline: 1.2829x; 1.2829x over previous
//
#include <hip/hip_runtime.h>

// segments: (8, 1, 512, 512) f32, values 0..63; downsample ::2 -> (8, 256, 256)
// R=7, K_SIDE=15, 225 offsets, zero-padded OOB (pad=0.0 CAN match seg==0)
// out: (8, 225, 256, 256) f32 = 471.9 MB -> write floor ~75 us @ 6.3 TB/s
//
// R9: DEPENDENCY-FREE STORE BURSTS. Evidence: fast-group kernels (R2/R3f/R7,
// ~160us = 2.95 TB/s) already share fill's aggregate address density across
// island sizes 1KB..256KB, NT/plain, direct/LDS reads; R8's enforced convoy
// made it worse. The one structural difference left vs fill (6.3 TB/s):
// every kernel so far issues ONE store per loop iteration, latency-chained
// behind an LDS read + compare, so outstanding-store depth stays ~1-2/wave.
// fill issues back-to-back independent stores (deep vmcnt pile-up).
// Here: register-block the neighbor window. Per dy, load the 20-float
// window ONCE (5 aligned ds_read_b128), then a fully-unrolled dx=0..14
// burst: 15 consecutive stores with no intervening memory dependency.
// Store:ds_read ratio 0.5 -> 3; stores per dependency chain 1 -> 15.
// Compile-time window indices only (no runtime reg indexing -> no scratch).
// Block = (8-row band, batch, dy-group of 5); stage 22-row halo once (24 KB
// LDS); 768 blocks = 3/CU = 24 waves/CU; plain stores; no hot-loop barriers.

#define RAD 7
#define KS 15
#define HW 256
#define IN_W 512
#define PLANE (HW * HW)         // 65536
#define CH 8                    // rows per band = waves per block
#define SROWS (CH + 2 * RAD)    // 22
#define SPITCH 272              // 8 left pad + 256 + 8 right pad
#define NPAIR (SPITCH / 2)      // 136
#define NTASK (SROWS * NPAIR)   // 2992

typedef float vf4 __attribute__((ext_vector_type(4)));

__global__ __launch_bounds__(512) void adj_regblock(const float* __restrict__ in,
                                                    float* __restrict__ out) {
    __shared__ float smem[SROWS][SPITCH];   // 23,936 B

    const int band = blockIdx.x;            // 0..31
    const int b    = blockIdx.y;            // 0..7
    const int dyg  = blockIdx.z;            // 0..2 -> dy in [5*dyg, 5*dyg+5)
    const int y0   = band * CH;
    const int dy0  = dyg * 5;
    const int tid  = threadIdx.x;

    const float* inb = in + (size_t)b * (IN_W * IN_W);

    // Stage ds rows [y0-7, y0+14] x ds cols [-8, 263], zero-padded.
    // LDS col pair (2pr, 2pr+1) = ds cols (2pr-8, 2pr-7) from one aligned
    // full-res vf4 (even elements = stride-2 downsample).
    for (int i = tid; i < NTASK; i += 512) {
        const int r  = i / NPAIR;
        const int pr = i - r * NPAIR;
        const int gy = y0 - RAD + r;        // ds row
        const int c0 = 2 * pr - 8;          // first ds col of pair
        float v0 = 0.0f, v1 = 0.0f;
        if ((unsigned)gy < (unsigned)HW && (unsigned)c0 < (unsigned)HW) {
            const vf4 q = *(const vf4*)(inb + (size_t)(2 * gy) * IN_W + 2 * c0);
            v0 = q.x;
            v1 = q.z;
        }
        smem[r][2 * pr]     = v0;
        smem[r][2 * pr + 1] = v1;
    }
    __syncthreads();

    const int wv   = tid >> 6;              // 0..7: row within band
    const int lane = tid & 63;
    const int x    = lane * 4;              // 4 output columns

    // own segment ids: fixed per wave, hoisted
    const vf4 own = *(const vf4*)&smem[wv + RAD][8 + x];
    const float s0 = own.x, s1 = own.y, s2 = own.z, s3 = own.w;

    // plane p = dy*15+dx walks sequentially; op advances by PLANE per store
    float* op = out + (size_t)b * (KS * KS) * (size_t)PLANE
                    + (size_t)(dy0 * KS) * PLANE
                    + (size_t)(y0 + wv) * HW + x;

    for (int dy = dy0; dy < dy0 + 5; ++dy) {
        // neighbor cols x+dx-7+k (dx 0..14, k 0..3) -> smem[wv+dy] cols
        // x+1 .. x+18  (smem col x+j == ds col x-8+j). Load window once.
        const float* wp = &smem[wv + dy][x];
        const vf4 w0 = *(const vf4*)(wp);
        const vf4 w1 = *(const vf4*)(wp + 4);
        const vf4 w2 = *(const vf4*)(wp + 8);
        const vf4 w3 = *(const vf4*)(wp + 12);
        const vf4 w4 = *(const vf4*)(wp + 16);
        const float win[20] = { w0.x, w0.y, w0.z, w0.w,
                                w1.x, w1.y, w1.z, w1.w,
                                w2.x, w2.y, w2.z, w2.w,
                                w3.x, w3.y, w3.z, w3.w,
                                w4.x, w4.y, w4.z, w4.w };
        #pragma unroll
        for (int dx = 0; dx < KS; ++dx) {   // 15 dependency-free stores
            vf4 r;
            r.x = (s0 == win[dx + 1]) ? 1.0f : 0.0f;
            r.y = (s1 == win[dx + 2]) ? 1.0f : 0.0f;
            r.z = (s2 == win[dx + 3]) ? 1.0f : 0.0f;
            r.w = (s3 == win[dx + 4]) ? 1.0f : 0.0f;
            *(vf4*)op = r;                  // plain store (match fill)
            op += PLANE;
        }
    }
}

extern "C" void kernel_launch(void* const* d_in, const int* in_sizes, int n_in,
                              void* d_out, int out_size, void* d_ws, size_t ws_size,
                              hipStream_t stream) {
    const float* segments = (const float*)d_in[0];
    float* out = (float*)d_out;
    dim3 grid(32, 8, 3);    // (band, batch, dy-group)
    dim3 block(512);
    adj_regblock<<<grid, block, 0, stream>>>(segments, out);
}

// Round 9
// 453.349 us; speedup vs baseline: 1.2908x; 1.0061x over previous
//
#include <hip/hip_runtime.h>

// segments: (8, 1, 512, 512) f32, values 0..63; downsample ::2 -> (8, 256, 256)
// R=7, K_SIDE=15, 225 offsets, zero-padded OOB (pad=0.0 CAN match seg==0)
// out: (8, 225, 256, 256) f32 = 471.9 MB -> write floor ~75 us @ 6.3 TB/s
//
// R11: isolate XCD-AFFINE WRITE REGIONS (R10 bundled it with sc0/sc1/nt
// streaming stores, which FAILED correctness: they bypass L2, leaving the
// harness's memset-primed zero lines stale -> reads saw 0. L2-bypass is
// excluded by coherence, not just untested.)
//  - b = bid & 7: round-robin dispatch puts all of batch i (contiguous
//    59 MB of out) on XCD i. Each private L2's write/eviction stream
//    becomes ~3 dense sliding 256 KB windows instead of 8 KB islands at
//    64 KB stride interleaved across 8 XCDs (all prior rounds).
//  - plain stores (NT proven null, bypass proven broken).
// Rest is R9's proven structure: block = (band, batch, dy-group of 5),
// stage 22-row halo once (24 KB LDS), own-IDs in regs, per-dy window in
// regs (5 aligned ds_read_b128), fully-unrolled 15-store burst.
// 768 blocks x 512 thr = 3 blocks/CU, no hot-loop barriers.
// Pre-commit: if ours stays ~156 us (dur ~456), declare ROOFLINE.

#define RAD 7
#define KS 15
#define HW 256
#define IN_W 512
#define PLANE (HW * HW)         // 65536
#define CH 8                    // rows per band = waves per block
#define SROWS (CH + 2 * RAD)    // 22
#define SPITCH 272              // 8 left pad + 256 + 8 right pad
#define NPAIR (SPITCH / 2)      // 136
#define NTASK (SROWS * NPAIR)   // 2992

typedef float vf4 __attribute__((ext_vector_type(4)));

__global__ __launch_bounds__(512) void adj_xcd(const float* __restrict__ in,
                                               float* __restrict__ out) {
    __shared__ float smem[SROWS][SPITCH];   // 23,936 B

    const int bid  = blockIdx.x;            // 0..767
    const int b    = bid & 7;               // batch == XCD (round-robin)
    const int rest = bid >> 3;              // 0..95
    const int band = rest & 31;             // 0..31
    const int dyg  = rest >> 5;             // 0..2 -> dy in [5*dyg, 5*dyg+5)
    const int y0   = band * CH;
    const int dy0  = dyg * 5;
    const int tid  = threadIdx.x;

    const float* inb = in + (size_t)b * (IN_W * IN_W);

    // Stage ds rows [y0-7, y0+14] x ds cols [-8, 263], zero-padded.
    // LDS col pair (2pr, 2pr+1) = ds cols (2pr-8, 2pr-7) from one aligned
    // full-res vf4 (even elements = stride-2 downsample).
    for (int i = tid; i < NTASK; i += 512) {
        const int r  = i / NPAIR;
        const int pr = i - r * NPAIR;
        const int gy = y0 - RAD + r;        // ds row
        const int c0 = 2 * pr - 8;          // first ds col of pair
        float v0 = 0.0f, v1 = 0.0f;
        if ((unsigned)gy < (unsigned)HW && (unsigned)c0 < (unsigned)HW) {
            const vf4 q = *(const vf4*)(inb + (size_t)(2 * gy) * IN_W + 2 * c0);
            v0 = q.x;
            v1 = q.z;
        }
        smem[r][2 * pr]     = v0;
        smem[r][2 * pr + 1] = v1;
    }
    __syncthreads();

    const int wv   = tid >> 6;              // 0..7: row within band
    const int lane = tid & 63;
    const int x    = lane * 4;              // 4 output columns

    // own segment ids: fixed per wave, hoisted
    const vf4 own = *(const vf4*)&smem[wv + RAD][8 + x];
    const float s0 = own.x, s1 = own.y, s2 = own.z, s3 = own.w;

    float* op = out + (size_t)b * (KS * KS) * (size_t)PLANE
                    + (size_t)(dy0 * KS) * PLANE
                    + (size_t)(y0 + wv) * HW + x;

    for (int dy = dy0; dy < dy0 + 5; ++dy) {
        // neighbor cols x+dx-7+k -> smem[wv+dy] cols x+dx+1+k; window once.
        const float* wp = &smem[wv + dy][x];
        const vf4 w0 = *(const vf4*)(wp);
        const vf4 w1 = *(const vf4*)(wp + 4);
        const vf4 w2 = *(const vf4*)(wp + 8);
        const vf4 w3 = *(const vf4*)(wp + 12);
        const vf4 w4 = *(const vf4*)(wp + 16);
        const float win[20] = { w0.x, w0.y, w0.z, w0.w,
                                w1.x, w1.y, w1.z, w1.w,
                                w2.x, w2.y, w2.z, w2.w,
                                w3.x, w3.y, w3.z, w3.w,
                                w4.x, w4.y, w4.z, w4.w };
        #pragma unroll
        for (int dx = 0; dx < KS; ++dx) {   // 15 dependency-free stores
            vf4 r;
            r.x = (s0 == win[dx + 1]) ? 1.0f : 0.0f;
            r.y = (s1 == win[dx + 2]) ? 1.0f : 0.0f;
            r.z = (s2 == win[dx + 3]) ? 1.0f : 0.0f;
            r.w = (s3 == win[dx + 4]) ? 1.0f : 0.0f;
            *(vf4*)op = r;                  // plain store (L2-coherent)
            op += PLANE;
        }
    }
}

extern "C" void kernel_launch(void* const* d_in, const int* in_sizes, int n_in,
                              void* d_out, int out_size, void* d_ws, size_t ws_size,
                              hipStream_t stream) {
    const float* segments = (const float*)d_in[0];
    float* out = (float*)d_out;
    adj_xcd<<<dim3(768), dim3(512), 0, stream>>>(segments, out);
}